// Round 11
// baseline (485.213 us; speedup 1.0000x reference)
//
#include <hip/hip_runtime.h>
#include <hip/hip_bf16.h>
#include <math.h>

#define MUL 8
#define HID 16
#define NB 10

typedef short short8 __attribute__((ext_vector_type(8)));
typedef float floatx4 __attribute__((ext_vector_type(4)));

__device__ __forceinline__ unsigned short f2bf_u(float x) {
    unsigned u = __float_as_uint(x);
    return (unsigned short)((u + 0x7fffu + ((u >> 16) & 1u)) >> 16);  // RNE
}

__device__ __forceinline__ unsigned pack2(float lo, float hi) {
#if __has_builtin(__builtin_amdgcn_cvt_pk_bf16_f32)
    typedef __bf16 bf2 __attribute__((ext_vector_type(2)));
    bf2 p = __builtin_amdgcn_cvt_pk_bf16_f32(lo, hi);
    return *reinterpret_cast<unsigned*>(&p);
#else
    return (unsigned)f2bf_u(lo) | ((unsigned)f2bf_u(hi) << 16);
#endif
}

// lane<->lane^1 exchange on the VALU pipe (DPP quad_perm(1,0,3,2)), not DS
__device__ __forceinline__ int dpp_xor1(int v) {
#if __has_builtin(__builtin_amdgcn_update_dpp)
    return __builtin_amdgcn_update_dpp(0, v, 0xB1, 0xF, 0xF, true);
#elif __has_builtin(__builtin_amdgcn_mov_dpp)
    return __builtin_amdgcn_mov_dpp(v, 0xB1, 0xF, 0xF, true);
#else
    return __shfl_xor(v, 1, 64);
#endif
}
__device__ __forceinline__ float dppf(float v) {
    return __int_as_float(dpp_xor1(__float_as_int(v)));
}

__device__ __forceinline__ unsigned perm_pair(unsigned a, unsigned b, unsigned sel) {
#if __has_builtin(__builtin_amdgcn_perm)
    return __builtin_amdgcn_perm(a, b, sel);   // bytes: b=0..3, a=4..7
#else
    unsigned long long cat = ((unsigned long long)a << 32) | b;
    unsigned r = 0;
#pragma unroll
    for (int i = 0; i < 4; ++i)
        r |= ((unsigned)(cat >> (8 * ((sel >> (8 * i)) & 7))) & 0xffu) << (8 * i);
    return r;
#endif
}

#define UNP(u, lo, hi) { lo = __uint_as_float((u) << 16); hi = __uint_as_float((u) & 0xffff0000u); }

// ws layout (floats): [0..511] W2r | [512..671] W1s
// | partial slots @ ws[672 + k*16], k<64 (64B line apart) | wave counter @ ws[1696]
// | Xb @ byte 8192 (N x 16 uints)
__global__ __launch_bounds__(256) void conv_prep_kernel(
    const float* __restrict__ X, unsigned* __restrict__ Xb, int nPack,
    const float* __restrict__ W1, const float* __restrict__ W2,
    float* __restrict__ ws)
{
    int i = blockIdx.x * 256 + threadIdx.x;
    if (i < nPack) {
        float2 f = ((const float2*)X)[i];
        Xb[i] = pack2(f.x, f.y);
    }
    if (blockIdx.x == 0) {
        int t = threadIdx.x;
        if (t < 65) ws[672 + t * 16] = 0.0f;   // t==64 zeroes the wave counter
        const float pw0 = 0.25f;            // sqrt(1/16)
        const float pw1 = 0.43301270189f;   // sqrt(3/16)
        const float i3  = 0.57735026919f;   // 1/sqrt(3)
#pragma unroll
        for (int k = t; k < HID * 32; k += 256) {
            int j  = k >> 5;
            int cu = k & 31;
            int c  = cu >> 3;
            float gs = (c < 2) ? pw0 : ((c == 2) ? pw1 : pw1 * i3);
            const float* p = W2 + j * 256 + cu * 8;
            float s = 0.0f;
#pragma unroll
            for (int v = 0; v < 8; ++v) s += p[v];
            ws[k] = s * 0.0625f * gs;       // 1/sqrt(HID) * 1/sqrt(NUM_NEIGHBORS)
        }
        if (t < NB * HID) ws[512 + t] = W1[t] * 1.41421356237f;
    }
}

// Edge kernel: one edge per lane, 64 per wave, barrier-free wave-private LDS.
// Lane pairs (2p, 2p+1) combine their values for each feature row into one
// packed bf16x2 b32 write: each lane KEEPS its own row's value and SENDS the
// value its partner needs via DPP (the R10 bug: it sent the kept value).
// 24 ds_write_b32 per lane instead of 48 ds_write_b16.
// Last-done wave performs the final reduction (no separate kernel).
__global__ __launch_bounds__(256, 4) void edge_kernel(
    const unsigned* __restrict__ Xb,   // N x 16 uints (32 bf16)
    const float* __restrict__ EV,      // E x 3
    const int*   __restrict__ SRC,     // E
    const float* __restrict__ W2r,     // 16 x 32 scaled
    const float* __restrict__ W1s,     // 10 x 16 scaled
    float* __restrict__ partial,       // 64 line-spread slots
    unsigned* __restrict__ cnt,        // wave-done counter
    float* __restrict__ out,
    int E, int totalWaves)
{
    __shared__ short lds[4][48][64];   // per-wave 48 rows x 64 edge slots
    int tid = threadIdx.x;
    int w = tid >> 6, l = tid & 63;
    int e0 = blockIdx.x * 256 + tid;
    bool valid = (e0 < E);
    int e = valid ? e0 : 0;

    int   si = __builtin_nontemporal_load(SRC + e);
    float ex = __builtin_nontemporal_load(EV + 3 * e);
    float ey = __builtin_nontemporal_load(EV + 3 * e + 1);
    float ez = __builtin_nontemporal_load(EV + 3 * e + 2);
    const uint4* xp = (const uint4*)(Xb + (size_t)si * 16);
    uint4 q0 = xp[0], q1 = xp[1], q2 = xp[2], q3 = xp[3];

    float r = sqrtf(ex * ex + ey * ey + ez * ez);
    float ir = 1.0f / r;
    float ux = ex * ir, uy = ey * ir, uz = ez * ir;
    float U = ux + uy + uz;

    // 2-sparse soft one-hot -> h (masked to 0 for invalid lanes)
    const float inv_step = 11.0f / 3.0f;
    float qf = r * inv_step;
    int qi = (int)floorf(qf);
    int ia = qi - 1, ib = qi;
    float diffa = qf - (float)(ia + 1);
    float diffb = qf - (float)(ib + 1);
    float dena = 1.0f - diffa * diffa;
    float denb = 1.0f - diffb * diffb;
    bool va = (ia >= 0) & (ia < NB) & valid;
    bool vb = (ib >= 0) & (ib < NB) & valid;
    float fa = va ? 1.14136f * __expf(2.0f - 2.0f / dena) : 0.0f;
    float fb = vb ? 1.14136f * __expf(2.0f - 2.0f / denb) : 0.0f;
    int ica = min(max(ia, 0), NB - 1);
    int icb = min(max(ib, 0), NB - 1);
    const float* ra = W1s + ica * HID;
    const float* rb = W1s + icb * HID;

    // paired-write bases: write i covers rows (2i, 2i+1); this lane's row is
    // g = 2i+sub at slot pair (2p, 2p+1). Row = 2(i&3)+sub + 8*(i>>2), and the
    // swizzle chunk (pc ^ (row&7)) depends only on i&3 -> 4 base pointers.
    int sub = l & 1, p = l >> 1;
    int pc = p >> 2, pw = p & 3;
    char* L = (char*)&lds[w][0][0];
    unsigned* wp[4];
#pragma unroll
    for (int a = 0; a < 4; ++a) {
        int g = 2 * a + sub;                       // row (mod 8) for i&3 == a
        wp[a] = (unsigned*)(L + g * 128 + ((pc ^ g) * 16) + pw * 4);
    }
    // per-lane perm selector for s-rows: even keeps lo halves, odd hi halves
    unsigned psel = sub ? 0x03020706u : 0x05040100u;

    // FIX vs R10: keep own-row value, SEND the value the partner needs.
    // even lane (sub=0): own=v0, send=v1, recv=partner's v0 -> word=(v0_e, v0_o)
    // odd  lane (sub=1): own=v1, send=v0, recv=partner's v1 -> word=(v1_e, v1_o)
#define WPAIR(i, v0, v1) {                                  \
        float own_  = (sub) ? (v1) : (v0);                  \
        float send_ = (sub) ? (v0) : (v1);                  \
        float recv_ = dppf(send_);                          \
        unsigned word_ = (sub) ? pack2(recv_, own_)         \
                               : pack2(own_, recv_);        \
        wp[(i) & 3][((i) >> 2) * 256] = word_; }

    // rows 0..15: h  (i = 0..7)
#pragma unroll
    for (int i = 0; i < 8; ++i) {
        float a0 = fa * ra[2 * i]     + fb * rb[2 * i];
        float a1 = fa * ra[2 * i + 1] + fb * rb[2 * i + 1];
        a0 = fmaxf(a0, 0.0f);
        a1 = fmaxf(a1, 0.0f);
        WPAIR(i, a0, a1);
    }

    // rows 16..23: s raw bf16 bits (i = 8..11) — one DPP + one v_perm each.
    // Own word wq holds (s[2k] lo, s[2k+1] hi); partner's via DPP; psel picks
    // the matching half from both with even lane's value in the lo slot.
    unsigned sq[4] = {q0.x, q0.y, q0.z, q0.w};
#pragma unroll
    for (int k = 0; k < 4; ++k) {
        unsigned wq = sq[k];
        unsigned xq = (unsigned)dpp_xor1((int)wq);
        unsigned word = perm_pair(xq, wq, psel);
        wp[(8 + k) & 3][((8 + k) >> 2) * 256] = word;
    }

    // unpack features
    float s[8], vv[24];
    UNP(q0.x, s[0], s[1]); UNP(q0.y, s[2], s[3]);
    UNP(q0.z, s[4], s[5]); UNP(q0.w, s[6], s[7]);
    UNP(q1.x, vv[0], vv[1]);   UNP(q1.y, vv[2], vv[3]);
    UNP(q1.z, vv[4], vv[5]);   UNP(q1.w, vv[6], vv[7]);
    UNP(q2.x, vv[8], vv[9]);   UNP(q2.y, vv[10], vv[11]);
    UNP(q2.z, vv[12], vv[13]); UNP(q2.w, vv[14], vv[15]);
    UNP(q3.x, vv[16], vv[17]); UNP(q3.y, vv[18], vv[19]);
    UNP(q3.z, vv[20], vv[21]); UNP(q3.w, vv[22], vv[23]);

    float dv[8], Vv[8], su[8];
#pragma unroll
    for (int u = 0; u < 8; ++u) {
        float vx = vv[3 * u], vy = vv[3 * u + 1], vz = vv[3 * u + 2];
        dv[u] = vx * ux + vy * uy + vz * uz;
        Vv[u] = vx + vy + vz;
        su[u] = s[u] * U;
    }
    // rows 24..31: d (i=12..15); rows 32..39: s*U (i=16..19); rows 40..47: V (i=20..23)
#pragma unroll
    for (int k = 0; k < 4; ++k) WPAIR(12 + k, dv[2 * k], dv[2 * k + 1]);
#pragma unroll
    for (int k = 0; k < 4; ++k) WPAIR(16 + k, su[2 * k], su[2 * k + 1]);
#pragma unroll
    for (int k = 0; k < 4; ++k) WPAIR(20 + k, Vv[2 * k], Vv[2 * k + 1]);
#undef WPAIR

    // wave-local transpose: same-wave ds ordering is program order; fence data
    asm volatile("s_waitcnt lgkmcnt(0)" ::: "memory");

    int ln = l & 15, qg = l >> 4;
    int c0 = (qg ^ (ln & 7)) * 16;
    int c1 = ((4 + qg) ^ (ln & 7)) * 16;
    short8 a0  = *(const short8*)(L + ln * 128 + c0);
    short8 a1  = *(const short8*)(L + ln * 128 + c1);
    short8 b00 = *(const short8*)(L + (16 + ln) * 128 + c0);   // B rows 0..15: s|d
    short8 b10 = *(const short8*)(L + (16 + ln) * 128 + c1);
    short8 b01 = *(const short8*)(L + (32 + ln) * 128 + c0);   // B rows 16..31: sU|V
    short8 b11 = *(const short8*)(L + (32 + ln) * 128 + c1);

    floatx4 acc0 = {0.f, 0.f, 0.f, 0.f}, acc1 = {0.f, 0.f, 0.f, 0.f};
    acc0 = __builtin_amdgcn_mfma_f32_16x16x32_bf16(a0, b00, acc0, 0, 0, 0);
    acc1 = __builtin_amdgcn_mfma_f32_16x16x32_bf16(a0, b01, acc1, 0, 0, 0);
    acc0 = __builtin_amdgcn_mfma_f32_16x16x32_bf16(a1, b10, acc0, 0, 0, 0);
    acc1 = __builtin_amdgcn_mfma_f32_16x16x32_bf16(a1, b11, acc1, 0, 0, 0);

    // epilogue: elementwise W . M once per wave.
    // C/D: col = lane&15 (=n), row = (lane>>4)*4 + reg  (m89-verified)
    float pr = 0.0f;
#pragma unroll
    for (int i = 0; i < 4; ++i) {
        int row = qg * 4 + i;
        pr += acc0[i] * W2r[row * 32 + ln] + acc1[i] * W2r[row * 32 + 16 + ln];
    }
#pragma unroll
    for (int off = 32; off > 0; off >>= 1)
        pr += __shfl_down(pr, off, 64);

    if (l == 0)
        atomicAdd(partial + (blockIdx.x & 63) * 16, pr);
    __threadfence();
    unsigned old = 0u;
    if (l == 0) old = atomicAdd(cnt, 1u);
    old = (unsigned)__builtin_amdgcn_readfirstlane((int)old);
    if (old == (unsigned)(totalWaves - 1)) {
        __threadfence();
        float v = atomicAdd(partial + l * 16, 0.0f);   // coherent read of slot l
#pragma unroll
        for (int off = 32; off > 0; off >>= 1)
            v += __shfl_down(v, off, 64);
        if (l == 0) out[0] = v;
    }
}

// Fallback (ws too small for bf16 table): per-edge f32 contraction, same tail.
__global__ __launch_bounds__(256, 6) void edge_kernel_f32(
    const float* __restrict__ X, const float* __restrict__ EV,
    const int* __restrict__ SRC, const float* __restrict__ W2r,
    const float* __restrict__ W1s, float* __restrict__ partial,
    unsigned* __restrict__ cnt, float* __restrict__ out,
    int E, int totalWaves)
{
    int tid = threadIdx.x;
    int l = tid & 63;
    int e = blockIdx.x * 256 + tid;
    float contrib = 0.0f;
    if (e < E) {
        int si = SRC[e];
        const float4* xp = (const float4*)(X + (size_t)si * 32);
        float4 x[8];
#pragma unroll
        for (int k = 0; k < 8; ++k) x[k] = xp[k];
        float ex = EV[3 * e], ey = EV[3 * e + 1], ez = EV[3 * e + 2];
        float r = sqrtf(ex * ex + ey * ey + ez * ez);
        float ir = 1.0f / r;
        float ux = ex * ir, uy = ey * ir, uz = ez * ir;
        float U = ux + uy + uz;
        const float inv_step = 11.0f / 3.0f;
        float qq = r * inv_step;
        int qi = (int)floorf(qq);
        int ia = qi - 1, ib = qi;
        float diffa = qq - (float)(ia + 1), diffb = qq - (float)(ib + 1);
        float dena = 1.0f - diffa * diffa, denb = 1.0f - diffb * diffb;
        float fa = ((ia >= 0) & (ia < NB)) ? 1.14136f * __expf(2.0f - 2.0f / dena) : 0.0f;
        float fb = ((ib >= 0) & (ib < NB)) ? 1.14136f * __expf(2.0f - 2.0f / denb) : 0.0f;
        const float* ra = W1s + min(max(ia, 0), NB - 1) * HID;
        const float* rb = W1s + min(max(ib, 0), NB - 1) * HID;
        float h[HID];
#pragma unroll
        for (int j = 0; j < HID; ++j) {
            float a = fa * ra[j] + fb * rb[j];
            h[j] = (a > 0.0f) ? a : 0.0f;
        }
        float s[8] = {x[0].x, x[0].y, x[0].z, x[0].w, x[1].x, x[1].y, x[1].z, x[1].w};
        float vv[24];
#pragma unroll
        for (int k = 0; k < 6; ++k) {
            vv[4 * k + 0] = x[2 + k].x; vv[4 * k + 1] = x[2 + k].y;
            vv[4 * k + 2] = x[2 + k].z; vv[4 * k + 3] = x[2 + k].w;
        }
        float d[8], V[8];
#pragma unroll
        for (int u = 0; u < 8; ++u) {
            float vx = vv[3 * u], vy = vv[3 * u + 1], vz = vv[3 * u + 2];
            d[u] = vx * ux + vy * uy + vz * uz;
            V[u] = vx + vy + vz;
        }
        float acc = 0.0f;
#pragma unroll
        for (int j = 0; j < HID; ++j) {
            const float* wt = W2r + j * 32;
            float A = 0, B = 0, C = 0, D = 0;
#pragma unroll
            for (int u = 0; u < 8; ++u) {
                A += wt[u] * s[u]; B += wt[8 + u] * d[u];
                C += wt[16 + u] * s[u]; D += wt[24 + u] * V[u];
            }
            acc += h[j] * (A + B + U * C + D);
        }
        contrib = acc;
    }
#pragma unroll
    for (int off = 32; off > 0; off >>= 1)
        contrib += __shfl_down(contrib, off, 64);
    if (l == 0)
        atomicAdd(partial + (blockIdx.x & 63) * 16, contrib);
    __threadfence();
    unsigned old = 0u;
    if (l == 0) old = atomicAdd(cnt, 1u);
    old = (unsigned)__builtin_amdgcn_readfirstlane((int)old);
    if (old == (unsigned)(totalWaves - 1)) {
        __threadfence();
        float v = atomicAdd(partial + l * 16, 0.0f);
#pragma unroll
        for (int off = 32; off > 0; off >>= 1)
            v += __shfl_down(v, off, 64);
        if (l == 0) out[0] = v;
    }
}

extern "C" void kernel_launch(void* const* d_in, const int* in_sizes, int n_in,
                              void* d_out, int out_size, void* d_ws, size_t ws_size,
                              hipStream_t stream) {
    const float* X   = (const float*)d_in[0];
    const float* EV  = (const float*)d_in[1];
    const float* W1  = (const float*)d_in[2];
    const float* W2  = (const float*)d_in[3];
    const int*   SRC = (const int*)d_in[4];
    int E = in_sizes[4];
    int N = in_sizes[0] / 32;

    float*    ws      = (float*)d_ws;
    float*    out     = (float*)d_out;
    float*    partial = ws + 672;
    unsigned* cnt     = (unsigned*)(ws + 1696);

    size_t xb_off = 8192;
    size_t need   = xb_off + (size_t)N * 64;
    int eblocks = (E + 255) / 256;
    int totalWaves = eblocks * 4;
    if (ws_size >= need) {
        unsigned* Xb = (unsigned*)((char*)d_ws + xb_off);
        int nPack = N * 16;
        conv_prep_kernel<<<(nPack + 255) / 256, 256, 0, stream>>>(X, Xb, nPack, W1, W2, ws);
        edge_kernel<<<eblocks, 256, 0, stream>>>(Xb, EV, SRC, ws, ws + 512,
                                                 partial, cnt, out, E, totalWaves);
    } else {
        conv_prep_kernel<<<1, 256, 0, stream>>>(X, (unsigned*)nullptr, 0, W1, W2, ws);
        edge_kernel_f32<<<eblocks, 256, 0, stream>>>(X, EV, SRC, ws, ws + 512,
                                                     partial, cnt, out, E, totalWaves);
    }
}

// Round 12
// 102.968 us; speedup vs baseline: 4.7123x; 4.7123x over previous
//
#include <hip/hip_runtime.h>
#include <hip/hip_bf16.h>
#include <math.h>

#define MUL 8
#define HID 16
#define NB 10

typedef short short8 __attribute__((ext_vector_type(8)));
typedef float floatx4 __attribute__((ext_vector_type(4)));

__device__ __forceinline__ unsigned short f2bf_u(float x) {
    unsigned u = __float_as_uint(x);
    return (unsigned short)((u + 0x7fffu + ((u >> 16) & 1u)) >> 16);  // RNE
}

__device__ __forceinline__ unsigned pack2(float lo, float hi) {
#if __has_builtin(__builtin_amdgcn_cvt_pk_bf16_f32)
    typedef __bf16 bf2 __attribute__((ext_vector_type(2)));
    bf2 p = __builtin_amdgcn_cvt_pk_bf16_f32(lo, hi);
    return *reinterpret_cast<unsigned*>(&p);
#else
    return (unsigned)f2bf_u(lo) | ((unsigned)f2bf_u(hi) << 16);
#endif
}

// lane<->lane^1 exchange on the VALU pipe (DPP quad_perm(1,0,3,2)), not DS
__device__ __forceinline__ int dpp_xor1(int v) {
#if __has_builtin(__builtin_amdgcn_update_dpp)
    return __builtin_amdgcn_update_dpp(0, v, 0xB1, 0xF, 0xF, true);
#elif __has_builtin(__builtin_amdgcn_mov_dpp)
    return __builtin_amdgcn_mov_dpp(v, 0xB1, 0xF, 0xF, true);
#else
    return __shfl_xor(v, 1, 64);
#endif
}
__device__ __forceinline__ float dppf(float v) {
    return __int_as_float(dpp_xor1(__float_as_int(v)));
}

__device__ __forceinline__ unsigned perm_pair(unsigned a, unsigned b, unsigned sel) {
#if __has_builtin(__builtin_amdgcn_perm)
    return __builtin_amdgcn_perm(a, b, sel);   // bytes: b=0..3, a=4..7
#else
    unsigned long long cat = ((unsigned long long)a << 32) | b;
    unsigned r = 0;
#pragma unroll
    for (int i = 0; i < 4; ++i)
        r |= ((unsigned)(cat >> (8 * ((sel >> (8 * i)) & 7))) & 0xffu) << (8 * i);
    return r;
#endif
}

#define UNP(u, lo, hi) { lo = __uint_as_float((u) << 16); hi = __uint_as_float((u) & 0xffff0000u); }

// ws layout (floats): [0..511] W2r | [512..671] W1s
// | partial slots @ ws[672 + k*16], k<64 (64B line apart)
// | Xb @ byte 8192 (N x 16 uints)
__global__ __launch_bounds__(256) void conv_prep_kernel(
    const float* __restrict__ X, unsigned* __restrict__ Xb, int nPack,
    const float* __restrict__ W1, const float* __restrict__ W2,
    float* __restrict__ ws)
{
    int i = blockIdx.x * 256 + threadIdx.x;
    if (i < nPack) {
        float2 f = ((const float2*)X)[i];
        Xb[i] = pack2(f.x, f.y);
    }
    if (blockIdx.x == 0) {
        int t = threadIdx.x;
        if (t < 64) ws[672 + t * 16] = 0.0f;
        const float pw0 = 0.25f;            // sqrt(1/16)
        const float pw1 = 0.43301270189f;   // sqrt(3/16)
        const float i3  = 0.57735026919f;   // 1/sqrt(3)
#pragma unroll
        for (int k = t; k < HID * 32; k += 256) {
            int j  = k >> 5;
            int cu = k & 31;
            int c  = cu >> 3;
            float gs = (c < 2) ? pw0 : ((c == 2) ? pw1 : pw1 * i3);
            const float* p = W2 + j * 256 + cu * 8;
            float s = 0.0f;
#pragma unroll
            for (int v = 0; v < 8; ++v) s += p[v];
            ws[k] = s * 0.0625f * gs;       // 1/sqrt(HID) * 1/sqrt(NUM_NEIGHBORS)
        }
        if (t < NB * HID) ws[512 + t] = W1[t] * 1.41421356237f;
    }
}

// Edge kernel: one edge per lane, 64 per wave, barrier-free wave-private LDS.
// Lane pairs (2p, 2p+1) combine their values for each feature row into one
// packed bf16x2 b32 write (24 ds_write_b32/lane vs 48 ds_write_b16).
// NO device fences in the hot path (R11: per-wave __threadfence cost ~400 µs
// — buffer_wbl2/inv serialize at the XCD fabric). Separate final kernel.
__global__ __launch_bounds__(256, 4) void edge_kernel(
    const unsigned* __restrict__ Xb,   // N x 16 uints (32 bf16)
    const float* __restrict__ EV,      // E x 3
    const int*   __restrict__ SRC,     // E
    const float* __restrict__ W2r,     // 16 x 32 scaled
    const float* __restrict__ W1s,     // 10 x 16 scaled
    float* __restrict__ partial, int E)
{
    __shared__ short lds[4][48][64];   // per-wave 48 rows x 64 edge slots
    int tid = threadIdx.x;
    int w = tid >> 6, l = tid & 63;
    int e0 = blockIdx.x * 256 + tid;
    bool valid = (e0 < E);
    int e = valid ? e0 : 0;

    int   si = __builtin_nontemporal_load(SRC + e);
    float ex = __builtin_nontemporal_load(EV + 3 * e);
    float ey = __builtin_nontemporal_load(EV + 3 * e + 1);
    float ez = __builtin_nontemporal_load(EV + 3 * e + 2);
    const uint4* xp = (const uint4*)(Xb + (size_t)si * 16);
    uint4 q0 = xp[0], q1 = xp[1], q2 = xp[2], q3 = xp[3];

    float r = sqrtf(ex * ex + ey * ey + ez * ez);
    float ir = 1.0f / r;
    float ux = ex * ir, uy = ey * ir, uz = ez * ir;
    float U = ux + uy + uz;

    // 2-sparse soft one-hot -> h (masked to 0 for invalid lanes)
    const float inv_step = 11.0f / 3.0f;
    float qf = r * inv_step;
    int qi = (int)floorf(qf);
    int ia = qi - 1, ib = qi;
    float diffa = qf - (float)(ia + 1);
    float diffb = qf - (float)(ib + 1);
    float dena = 1.0f - diffa * diffa;
    float denb = 1.0f - diffb * diffb;
    bool va = (ia >= 0) & (ia < NB) & valid;
    bool vb = (ib >= 0) & (ib < NB) & valid;
    float fa = va ? 1.14136f * __expf(2.0f - 2.0f / dena) : 0.0f;
    float fb = vb ? 1.14136f * __expf(2.0f - 2.0f / denb) : 0.0f;
    int ica = min(max(ia, 0), NB - 1);
    int icb = min(max(ib, 0), NB - 1);
    const float* ra = W1s + ica * HID;
    const float* rb = W1s + icb * HID;

    // paired-write bases: write i covers rows (2i, 2i+1); this lane's row is
    // g = 2i+sub at slot pair (2p, 2p+1). Row = 2(i&3)+sub + 8*(i>>2); the
    // swizzle chunk (pc ^ (row&7)) depends only on i&3 -> 4 base pointers.
    // Bank check: even lanes cover dwords {(pc^g)*4+pw} = {0..31} once each;
    // odd lanes likewise (row stride 128 B = bank-neutral) -> 2/bank = free.
    int sub = l & 1, p = l >> 1;
    int pc = p >> 2, pw = p & 3;
    char* L = (char*)&lds[w][0][0];
    unsigned* wp[4];
#pragma unroll
    for (int a = 0; a < 4; ++a) {
        int g = 2 * a + sub;                       // row (mod 8) for i&3 == a
        wp[a] = (unsigned*)(L + g * 128 + ((pc ^ g) * 16) + pw * 4);
    }
    // per-lane perm selector for s-rows: even keeps lo halves, odd hi halves
    unsigned psel = sub ? 0x03020706u : 0x05040100u;

    // keep own-row value, SEND the value the partner needs (R10 bug fixed).
#define WPAIR(i, v0, v1) {                                  \
        float own_  = (sub) ? (v1) : (v0);                  \
        float send_ = (sub) ? (v0) : (v1);                  \
        float recv_ = dppf(send_);                          \
        unsigned word_ = (sub) ? pack2(recv_, own_)         \
                               : pack2(own_, recv_);        \
        wp[(i) & 3][((i) >> 2) * 256] = word_; }

    // rows 0..15: h  (i = 0..7)
#pragma unroll
    for (int i = 0; i < 8; ++i) {
        float a0 = fa * ra[2 * i]     + fb * rb[2 * i];
        float a1 = fa * ra[2 * i + 1] + fb * rb[2 * i + 1];
        a0 = fmaxf(a0, 0.0f);
        a1 = fmaxf(a1, 0.0f);
        WPAIR(i, a0, a1);
    }

    // rows 16..23: s raw bf16 bits (i = 8..11) — one DPP + one v_perm each
    unsigned sq[4] = {q0.x, q0.y, q0.z, q0.w};
#pragma unroll
    for (int k = 0; k < 4; ++k) {
        unsigned wq = sq[k];
        unsigned xq = (unsigned)dpp_xor1((int)wq);
        unsigned word = perm_pair(xq, wq, psel);
        wp[(8 + k) & 3][((8 + k) >> 2) * 256] = word;
    }

    // unpack features
    float s[8], vv[24];
    UNP(q0.x, s[0], s[1]); UNP(q0.y, s[2], s[3]);
    UNP(q0.z, s[4], s[5]); UNP(q0.w, s[6], s[7]);
    UNP(q1.x, vv[0], vv[1]);   UNP(q1.y, vv[2], vv[3]);
    UNP(q1.z, vv[4], vv[5]);   UNP(q1.w, vv[6], vv[7]);
    UNP(q2.x, vv[8], vv[9]);   UNP(q2.y, vv[10], vv[11]);
    UNP(q2.z, vv[12], vv[13]); UNP(q2.w, vv[14], vv[15]);
    UNP(q3.x, vv[16], vv[17]); UNP(q3.y, vv[18], vv[19]);
    UNP(q3.z, vv[20], vv[21]); UNP(q3.w, vv[22], vv[23]);

    float dv[8], Vv[8], su[8];
#pragma unroll
    for (int u = 0; u < 8; ++u) {
        float vx = vv[3 * u], vy = vv[3 * u + 1], vz = vv[3 * u + 2];
        dv[u] = vx * ux + vy * uy + vz * uz;
        Vv[u] = vx + vy + vz;
        su[u] = s[u] * U;
    }
    // rows 24..31: d (i=12..15); rows 32..39: s*U (i=16..19); rows 40..47: V (i=20..23)
#pragma unroll
    for (int k = 0; k < 4; ++k) WPAIR(12 + k, dv[2 * k], dv[2 * k + 1]);
#pragma unroll
    for (int k = 0; k < 4; ++k) WPAIR(16 + k, su[2 * k], su[2 * k + 1]);
#pragma unroll
    for (int k = 0; k < 4; ++k) WPAIR(20 + k, Vv[2 * k], Vv[2 * k + 1]);
#undef WPAIR

    // wave-local transpose: same-wave ds ordering is program order; fence data
    asm volatile("s_waitcnt lgkmcnt(0)" ::: "memory");

    int ln = l & 15, qg = l >> 4;
    int c0 = (qg ^ (ln & 7)) * 16;
    int c1 = ((4 + qg) ^ (ln & 7)) * 16;
    short8 a0  = *(const short8*)(L + ln * 128 + c0);
    short8 a1  = *(const short8*)(L + ln * 128 + c1);
    short8 b00 = *(const short8*)(L + (16 + ln) * 128 + c0);   // B rows 0..15: s|d
    short8 b10 = *(const short8*)(L + (16 + ln) * 128 + c1);
    short8 b01 = *(const short8*)(L + (32 + ln) * 128 + c0);   // B rows 16..31: sU|V
    short8 b11 = *(const short8*)(L + (32 + ln) * 128 + c1);

    floatx4 acc0 = {0.f, 0.f, 0.f, 0.f}, acc1 = {0.f, 0.f, 0.f, 0.f};
    acc0 = __builtin_amdgcn_mfma_f32_16x16x32_bf16(a0, b00, acc0, 0, 0, 0);
    acc1 = __builtin_amdgcn_mfma_f32_16x16x32_bf16(a0, b01, acc1, 0, 0, 0);
    acc0 = __builtin_amdgcn_mfma_f32_16x16x32_bf16(a1, b10, acc0, 0, 0, 0);
    acc1 = __builtin_amdgcn_mfma_f32_16x16x32_bf16(a1, b11, acc1, 0, 0, 0);

    // epilogue: elementwise W . M once per wave.
    // C/D: col = lane&15 (=n), row = (lane>>4)*4 + reg  (m89-verified)
    float pr = 0.0f;
#pragma unroll
    for (int i = 0; i < 4; ++i) {
        int row = qg * 4 + i;
        pr += acc0[i] * W2r[row * 32 + ln] + acc1[i] * W2r[row * 32 + 16 + ln];
    }
#pragma unroll
    for (int off = 32; off > 0; off >>= 1)
        pr += __shfl_down(pr, off, 64);

    if (l == 0)
        atomicAdd(partial + (blockIdx.x & 63) * 16, pr);
}

__global__ void final_kernel(const float* __restrict__ partial,
                             float* __restrict__ out) {
    int t = threadIdx.x;  // 64
    float v = partial[t * 16];
#pragma unroll
    for (int off = 32; off > 0; off >>= 1)
        v += __shfl_down(v, off, 64);
    if (t == 0) out[0] = v;
}

// Fallback (ws too small for bf16 table): per-edge f32 contraction.
__global__ __launch_bounds__(256, 6) void edge_kernel_f32(
    const float* __restrict__ X, const float* __restrict__ EV,
    const int* __restrict__ SRC, const float* __restrict__ W2r,
    const float* __restrict__ W1s, float* __restrict__ partial, int E)
{
    int tid = threadIdx.x;
    int l = tid & 63;
    int e = blockIdx.x * 256 + tid;
    float contrib = 0.0f;
    if (e < E) {
        int si = SRC[e];
        const float4* xp = (const float4*)(X + (size_t)si * 32);
        float4 x[8];
#pragma unroll
        for (int k = 0; k < 8; ++k) x[k] = xp[k];
        float ex = EV[3 * e], ey = EV[3 * e + 1], ez = EV[3 * e + 2];
        float r = sqrtf(ex * ex + ey * ey + ez * ez);
        float ir = 1.0f / r;
        float ux = ex * ir, uy = ey * ir, uz = ez * ir;
        float U = ux + uy + uz;
        const float inv_step = 11.0f / 3.0f;
        float qq = r * inv_step;
        int qi = (int)floorf(qq);
        int ia = qi - 1, ib = qi;
        float diffa = qq - (float)(ia + 1), diffb = qq - (float)(ib + 1);
        float dena = 1.0f - diffa * diffa, denb = 1.0f - diffb * diffb;
        float fa = ((ia >= 0) & (ia < NB)) ? 1.14136f * __expf(2.0f - 2.0f / dena) : 0.0f;
        float fb = ((ib >= 0) & (ib < NB)) ? 1.14136f * __expf(2.0f - 2.0f / denb) : 0.0f;
        const float* ra = W1s + min(max(ia, 0), NB - 1) * HID;
        const float* rb = W1s + min(max(ib, 0), NB - 1) * HID;
        float h[HID];
#pragma unroll
        for (int j = 0; j < HID; ++j) {
            float a = fa * ra[j] + fb * rb[j];
            h[j] = (a > 0.0f) ? a : 0.0f;
        }
        float s[8] = {x[0].x, x[0].y, x[0].z, x[0].w, x[1].x, x[1].y, x[1].z, x[1].w};
        float vv[24];
#pragma unroll
        for (int k = 0; k < 6; ++k) {
            vv[4 * k + 0] = x[2 + k].x; vv[4 * k + 1] = x[2 + k].y;
            vv[4 * k + 2] = x[2 + k].z; vv[4 * k + 3] = x[2 + k].w;
        }
        float d[8], V[8];
#pragma unroll
        for (int u = 0; u < 8; ++u) {
            float vx = vv[3 * u], vy = vv[3 * u + 1], vz = vv[3 * u + 2];
            d[u] = vx * ux + vy * uy + vz * uz;
            V[u] = vx + vy + vz;
        }
        float acc = 0.0f;
#pragma unroll
        for (int j = 0; j < HID; ++j) {
            const float* wt = W2r + j * 32;
            float A = 0, B = 0, C = 0, D = 0;
#pragma unroll
            for (int u = 0; u < 8; ++u) {
                A += wt[u] * s[u]; B += wt[8 + u] * d[u];
                C += wt[16 + u] * s[u]; D += wt[24 + u] * V[u];
            }
            acc += h[j] * (A + B + U * C + D);
        }
        contrib = acc;
    }
#pragma unroll
    for (int off = 32; off > 0; off >>= 1)
        contrib += __shfl_down(contrib, off, 64);
    if (l == 0)
        atomicAdd(partial + (blockIdx.x & 63) * 16, contrib);
}

extern "C" void kernel_launch(void* const* d_in, const int* in_sizes, int n_in,
                              void* d_out, int out_size, void* d_ws, size_t ws_size,
                              hipStream_t stream) {
    const float* X   = (const float*)d_in[0];
    const float* EV  = (const float*)d_in[1];
    const float* W1  = (const float*)d_in[2];
    const float* W2  = (const float*)d_in[3];
    const int*   SRC = (const int*)d_in[4];
    int E = in_sizes[4];
    int N = in_sizes[0] / 32;

    float* ws      = (float*)d_ws;
    float* out     = (float*)d_out;
    float* partial = ws + 672;

    size_t xb_off = 8192;
    size_t need   = xb_off + (size_t)N * 64;
    int eblocks = (E + 255) / 256;
    if (ws_size >= need) {
        unsigned* Xb = (unsigned*)((char*)d_ws + xb_off);
        int nPack = N * 16;
        conv_prep_kernel<<<(nPack + 255) / 256, 256, 0, stream>>>(X, Xb, nPack, W1, W2, ws);
        edge_kernel<<<eblocks, 256, 0, stream>>>(Xb, EV, SRC, ws, ws + 512, partial, E);
    } else {
        conv_prep_kernel<<<1, 256, 0, stream>>>(X, (unsigned*)nullptr, 0, W1, W2, ws);
        edge_kernel_f32<<<eblocks, 256, 0, stream>>>(X, EV, SRC, ws, ws + 512, partial, E);
    }
    final_kernel<<<1, 64, 0, stream>>>(partial, out);
}

// Round 13
// 94.510 us; speedup vs baseline: 5.1340x; 1.0895x over previous
//
#include <hip/hip_runtime.h>
#include <hip/hip_bf16.h>
#include <math.h>

#define MUL 8
#define HID 16
#define NB 10

typedef short short8 __attribute__((ext_vector_type(8)));
typedef float floatx4 __attribute__((ext_vector_type(4)));

__device__ __forceinline__ unsigned short f2bf_u(float x) {
    unsigned u = __float_as_uint(x);
    return (unsigned short)((u + 0x7fffu + ((u >> 16) & 1u)) >> 16);  // RNE
}
__device__ __forceinline__ short f2bf(float x) { return (short)f2bf_u(x); }

__device__ __forceinline__ unsigned pack2(float lo, float hi) {
#if __has_builtin(__builtin_amdgcn_cvt_pk_bf16_f32)
    typedef __bf16 bf2 __attribute__((ext_vector_type(2)));
    bf2 p = __builtin_amdgcn_cvt_pk_bf16_f32(lo, hi);
    return *reinterpret_cast<unsigned*>(&p);
#else
    return (unsigned)f2bf_u(lo) | ((unsigned)f2bf_u(hi) << 16);
#endif
}

#define UNP(u, lo, hi) { lo = __uint_as_float((u) << 16); hi = __uint_as_float((u) & 0xffff0000u); }

// ws layout (floats): [0..511] W2r | [512..671] W1s
// | partial slots @ ws[672 + k*16], k<64 (one 64B line per slot — R9-measured:
//   single-address atomics cost +25 µs of serialized L2 RMW)
// | Xb @ byte 8192 (N x 16 uints)
__global__ __launch_bounds__(256) void conv_prep_kernel(
    const float* __restrict__ X, unsigned* __restrict__ Xb, int nPack,
    const float* __restrict__ W1, const float* __restrict__ W2,
    float* __restrict__ ws)
{
    int i = blockIdx.x * 256 + threadIdx.x;
    if (i < nPack) {
        float2 f = ((const float2*)X)[i];
        Xb[i] = pack2(f.x, f.y);
    }
    if (blockIdx.x == 0) {
        int t = threadIdx.x;
        if (t < 64) ws[672 + t * 16] = 0.0f;
        const float pw0 = 0.25f;            // sqrt(1/16)
        const float pw1 = 0.43301270189f;   // sqrt(3/16)
        const float i3  = 0.57735026919f;   // 1/sqrt(3)
#pragma unroll
        for (int k = t; k < HID * 32; k += 256) {
            int j  = k >> 5;
            int cu = k & 31;
            int c  = cu >> 3;
            float gs = (c < 2) ? pw0 : ((c == 2) ? pw1 : pw1 * i3);
            const float* p = W2 + j * 256 + cu * 8;
            float s = 0.0f;
#pragma unroll
            for (int v = 0; v < 8; ++v) s += p[v];
            ws[k] = s * 0.0625f * gs;       // 1/sqrt(HID) * 1/sqrt(NUM_NEIGHBORS)
        }
        if (t < NB * HID) ws[512 + t] = W1[t] * 1.41421356237f;
    }
}

// Edge kernel (R9 configuration — best measured, 96.3 µs total): one edge per
// lane, 64 per wave, barrier-free wave-private LDS (same-wave DS ordering is
// program order; lgkmcnt fence only). Plain b16 LDS writes (R12's DPP-paired
// b32 writes were neutral-to-worse — kernel is gather-latency bound, not
// DS-issue bound). NO device fences in the hot path (R11: ~400 µs). Weights
// applied once per wave in the epilogue; line-spread partial atomics.
__global__ __launch_bounds__(256, 4) void edge_kernel(
    const unsigned* __restrict__ Xb,   // N x 16 uints (32 bf16)
    const float* __restrict__ EV,      // E x 3
    const int*   __restrict__ SRC,     // E
    const float* __restrict__ W2r,     // 16 x 32 scaled
    const float* __restrict__ W1s,     // 10 x 16 scaled
    float* __restrict__ partial, int E)
{
    __shared__ short A_lds[4][16][64];  // [wave][j][kk]  (xor-swizzled)
    __shared__ short B_lds[4][32][64];  // [wave][n][kk]
    int tid = threadIdx.x;
    int w = tid >> 6, l = tid & 63;
    int e0 = blockIdx.x * 256 + tid;
    bool valid = (e0 < E);
    int e = valid ? e0 : 0;

    int   si = __builtin_nontemporal_load(SRC + e);
    float ex = __builtin_nontemporal_load(EV + 3 * e);
    float ey = __builtin_nontemporal_load(EV + 3 * e + 1);
    float ez = __builtin_nontemporal_load(EV + 3 * e + 2);
    const uint4* xp = (const uint4*)(Xb + (size_t)si * 16);
    uint4 q0 = xp[0], q1 = xp[1], q2 = xp[2], q3 = xp[3];

    float r = sqrtf(ex * ex + ey * ey + ez * ez);
    float ir = 1.0f / r;
    float ux = ex * ir, uy = ey * ir, uz = ez * ir;
    float U = ux + uy + uz;

    // 2-sparse soft one-hot -> h (masked to 0 for invalid lanes)
    const float inv_step = 11.0f / 3.0f;
    float qq = r * inv_step;
    int qi = (int)floorf(qq);
    int ia = qi - 1, ib = qi;
    float diffa = qq - (float)(ia + 1);
    float diffb = qq - (float)(ib + 1);
    float dena = 1.0f - diffa * diffa;
    float denb = 1.0f - diffb * diffb;
    bool va = (ia >= 0) & (ia < NB) & valid;
    bool vb = (ib >= 0) & (ib < NB) & valid;
    float fa = va ? 1.14136f * __expf(2.0f - 2.0f / dena) : 0.0f;
    float fb = vb ? 1.14136f * __expf(2.0f - 2.0f / denb) : 0.0f;
    int ica = min(max(ia, 0), NB - 1);
    int icb = min(max(ib, 0), NB - 1);
    const float* ra = W1s + ica * HID;
    const float* rb = W1s + icb * HID;

    // write A column (this lane's edge): A[j][kk=l], swizzled
#pragma unroll
    for (int j = 0; j < HID; ++j) {
        float a = fa * ra[j] + fb * rb[j];
        float hj = (a > 0.0f) ? a : 0.0f;
        A_lds[w][j][((((l >> 3) ^ (j & 7)) << 3) | (l & 7))] = f2bf(hj);
    }

    // features: f[0..7]=s (raw bf16 bits), f[8..15]=d, f[16..23]=s*U, f[24..31]=V
    float s[8], vv[24];
    UNP(q0.x, s[0], s[1]); UNP(q0.y, s[2], s[3]);
    UNP(q0.z, s[4], s[5]); UNP(q0.w, s[6], s[7]);
    UNP(q1.x, vv[0], vv[1]);   UNP(q1.y, vv[2], vv[3]);
    UNP(q1.z, vv[4], vv[5]);   UNP(q1.w, vv[6], vv[7]);
    UNP(q2.x, vv[8], vv[9]);   UNP(q2.y, vv[10], vv[11]);
    UNP(q2.z, vv[12], vv[13]); UNP(q2.w, vv[14], vv[15]);
    UNP(q3.x, vv[16], vv[17]); UNP(q3.y, vv[18], vv[19]);
    UNP(q3.z, vv[20], vv[21]); UNP(q3.w, vv[22], vv[23]);

    unsigned sq[4] = {q0.x, q0.y, q0.z, q0.w};
#pragma unroll
    for (int u = 0; u < 8; ++u) {
        unsigned bits = (u & 1) ? (sq[u >> 1] >> 16) : (sq[u >> 1] & 0xffffu);
        B_lds[w][u][((((l >> 3) ^ (u & 7)) << 3) | (l & 7))] = (short)bits;
    }
#pragma unroll
    for (int u = 0; u < 8; ++u) {
        float vx = vv[3 * u], vy = vv[3 * u + 1], vz = vv[3 * u + 2];
        float d = vx * ux + vy * uy + vz * uz;
        float V = vx + vy + vz;
        int n1 = 8 + u, n2 = 16 + u, n3 = 24 + u;
        B_lds[w][n1][((((l >> 3) ^ (n1 & 7)) << 3) | (l & 7))] = f2bf(d);
        B_lds[w][n2][((((l >> 3) ^ (n2 & 7)) << 3) | (l & 7))] = f2bf(s[u] * U);
        B_lds[w][n3][((((l >> 3) ^ (n3 & 7)) << 3) | (l & 7))] = f2bf(V);
    }

    // wave-local transpose: same-wave ds ordering is program order; fence data
    asm volatile("s_waitcnt lgkmcnt(0)" ::: "memory");

    int ln = l & 15, q = l >> 4;
    short8 a0  = *(const short8*)&A_lds[w][ln][(((q)     ^ (ln & 7)) << 3)];
    short8 a1  = *(const short8*)&A_lds[w][ln][(((4 + q) ^ (ln & 7)) << 3)];
    short8 b00 = *(const short8*)&B_lds[w][ln][(((q)     ^ (ln & 7)) << 3)];
    short8 b01 = *(const short8*)&B_lds[w][ln + 16][(((q)     ^ (ln & 7)) << 3)];
    short8 b10 = *(const short8*)&B_lds[w][ln][(((4 + q) ^ (ln & 7)) << 3)];
    short8 b11 = *(const short8*)&B_lds[w][ln + 16][(((4 + q) ^ (ln & 7)) << 3)];

    floatx4 acc0 = {0.f, 0.f, 0.f, 0.f}, acc1 = {0.f, 0.f, 0.f, 0.f};
    acc0 = __builtin_amdgcn_mfma_f32_16x16x32_bf16(a0, b00, acc0, 0, 0, 0);
    acc1 = __builtin_amdgcn_mfma_f32_16x16x32_bf16(a0, b01, acc1, 0, 0, 0);
    acc0 = __builtin_amdgcn_mfma_f32_16x16x32_bf16(a1, b10, acc0, 0, 0, 0);
    acc1 = __builtin_amdgcn_mfma_f32_16x16x32_bf16(a1, b11, acc1, 0, 0, 0);

    // epilogue: elementwise W . M once per wave.
    // C/D: col = lane&15 (=n), row = (lane>>4)*4 + reg  (m89-verified)
    float p = 0.0f;
#pragma unroll
    for (int i = 0; i < 4; ++i) {
        int row = q * 4 + i;
        p += acc0[i] * W2r[row * 32 + ln] + acc1[i] * W2r[row * 32 + 16 + ln];
    }
#pragma unroll
    for (int off = 32; off > 0; off >>= 1)
        p += __shfl_down(p, off, 64);

    if (l == 0)
        atomicAdd(partial + (blockIdx.x & 63) * 16, p);
}

__global__ void final_kernel(const float* __restrict__ partial,
                             float* __restrict__ out) {
    int t = threadIdx.x;  // 64
    float v = partial[t * 16];
#pragma unroll
    for (int off = 32; off > 0; off >>= 1)
        v += __shfl_down(v, off, 64);
    if (t == 0) out[0] = v;
}

// Fallback (ws too small for bf16 table): per-edge f32 contraction.
__global__ __launch_bounds__(256, 6) void edge_kernel_f32(
    const float* __restrict__ X, const float* __restrict__ EV,
    const int* __restrict__ SRC, const float* __restrict__ W2r,
    const float* __restrict__ W1s, float* __restrict__ partial, int E)
{
    int tid = threadIdx.x;
    int l = tid & 63;
    int e = blockIdx.x * 256 + tid;
    float contrib = 0.0f;
    if (e < E) {
        int si = SRC[e];
        const float4* xp = (const float4*)(X + (size_t)si * 32);
        float4 x[8];
#pragma unroll
        for (int k = 0; k < 8; ++k) x[k] = xp[k];
        float ex = EV[3 * e], ey = EV[3 * e + 1], ez = EV[3 * e + 2];
        float r = sqrtf(ex * ex + ey * ey + ez * ez);
        float ir = 1.0f / r;
        float ux = ex * ir, uy = ey * ir, uz = ez * ir;
        float U = ux + uy + uz;
        const float inv_step = 11.0f / 3.0f;
        float qq = r * inv_step;
        int qi = (int)floorf(qq);
        int ia = qi - 1, ib = qi;
        float diffa = qq - (float)(ia + 1), diffb = qq - (float)(ib + 1);
        float dena = 1.0f - diffa * diffa, denb = 1.0f - diffb * diffb;
        float fa = ((ia >= 0) & (ia < NB)) ? 1.14136f * __expf(2.0f - 2.0f / dena) : 0.0f;
        float fb = ((ib >= 0) & (ib < NB)) ? 1.14136f * __expf(2.0f - 2.0f / denb) : 0.0f;
        const float* ra = W1s + min(max(ia, 0), NB - 1) * HID;
        const float* rb = W1s + min(max(ib, 0), NB - 1) * HID;
        float h[HID];
#pragma unroll
        for (int j = 0; j < HID; ++j) {
            float a = fa * ra[j] + fb * rb[j];
            h[j] = (a > 0.0f) ? a : 0.0f;
        }
        float s[8] = {x[0].x, x[0].y, x[0].z, x[0].w, x[1].x, x[1].y, x[1].z, x[1].w};
        float vv[24];
#pragma unroll
        for (int k = 0; k < 6; ++k) {
            vv[4 * k + 0] = x[2 + k].x; vv[4 * k + 1] = x[2 + k].y;
            vv[4 * k + 2] = x[2 + k].z; vv[4 * k + 3] = x[2 + k].w;
        }
        float d[8], V[8];
#pragma unroll
        for (int u = 0; u < 8; ++u) {
            float vx = vv[3 * u], vy = vv[3 * u + 1], vz = vv[3 * u + 2];
            d[u] = vx * ux + vy * uy + vz * uz;
            V[u] = vx + vy + vz;
        }
        float acc = 0.0f;
#pragma unroll
        for (int j = 0; j < HID; ++j) {
            const float* wt = W2r + j * 32;
            float A = 0, B = 0, C = 0, D = 0;
#pragma unroll
            for (int u = 0; u < 8; ++u) {
                A += wt[u] * s[u]; B += wt[8 + u] * d[u];
                C += wt[16 + u] * s[u]; D += wt[24 + u] * V[u];
            }
            acc += h[j] * (A + B + U * C + D);
        }
        contrib = acc;
    }
#pragma unroll
    for (int off = 32; off > 0; off >>= 1)
        contrib += __shfl_down(contrib, off, 64);
    if (l == 0)
        atomicAdd(partial + (blockIdx.x & 63) * 16, contrib);
}

extern "C" void kernel_launch(void* const* d_in, const int* in_sizes, int n_in,
                              void* d_out, int out_size, void* d_ws, size_t ws_size,
                              hipStream_t stream) {
    const float* X   = (const float*)d_in[0];
    const float* EV  = (const float*)d_in[1];
    const float* W1  = (const float*)d_in[2];
    const float* W2  = (const float*)d_in[3];
    const int*   SRC = (const int*)d_in[4];
    int E = in_sizes[4];
    int N = in_sizes[0] / 32;

    float* ws      = (float*)d_ws;
    float* out     = (float*)d_out;
    float* partial = ws + 672;

    size_t xb_off = 8192;
    size_t need   = xb_off + (size_t)N * 64;
    int eblocks = (E + 255) / 256;
    if (ws_size >= need) {
        unsigned* Xb = (unsigned*)((char*)d_ws + xb_off);
        int nPack = N * 16;
        conv_prep_kernel<<<(nPack + 255) / 256, 256, 0, stream>>>(X, Xb, nPack, W1, W2, ws);
        edge_kernel<<<eblocks, 256, 0, stream>>>(Xb, EV, SRC, ws, ws + 512, partial, E);
    } else {
        conv_prep_kernel<<<1, 256, 0, stream>>>(X, (unsigned*)nullptr, 0, W1, W2, ws);
        edge_kernel_f32<<<eblocks, 256, 0, stream>>>(X, EV, SRC, ws, ws + 512, partial, E);
    }
    final_kernel<<<1, 64, 0, stream>>>(partial, out);
}